// Round 3
// baseline (328.103 us; speedup 1.0000x reference)
//
#include <hip/hip_runtime.h>
#include <stdint.h>

// y[m][n] = sum_k x[m][k] * W[k][n] + b[n]
// M=262144, K=128, N=128. Floor: ~134 MB x-read (L3-hot) + ~134 MB y-write.
// bf16 MFMA 16x16x32, swapped operands (A=W^T, B=x) -> lane's 4 C-regs are 4
// consecutive y columns -> f32x4 nontemporal stores.
// Grid = 1024 = exact full residency (4 blocks/CU); each block grid-strides
// over 4 chunks of 64 rows with a load->compute->convert software pipeline.

typedef __attribute__((ext_vector_type(8))) short bf16x8;   // 8 bf16 = 4 VGPRs
typedef __attribute__((ext_vector_type(4))) float f32x4;    // MFMA C/D

#define GRID   1024
#define NCHUNK 4096   // 262144 rows / 64 rows per chunk

__device__ inline unsigned short f2bf(float f) {
  union { float f; uint32_t u; } v; v.f = f;
  uint32_t r = v.u + 0x7fffu + ((v.u >> 16) & 1u);
  return (unsigned short)(r >> 16);
}

__device__ inline void cvt8(const f32x4* src, bf16x8* dst) {
  #pragma unroll
  for (int kk = 0; kk < 4; ++kk) {
    bf16x8 av;
    av[0] = f2bf(src[2*kk][0]); av[1] = f2bf(src[2*kk][1]);
    av[2] = f2bf(src[2*kk][2]); av[3] = f2bf(src[2*kk][3]);
    av[4] = f2bf(src[2*kk+1][0]); av[5] = f2bf(src[2*kk+1][1]);
    av[6] = f2bf(src[2*kk+1][2]); av[7] = f2bf(src[2*kk+1][3]);
    dst[kk] = av;
  }
}

__global__ __launch_bounds__(256, 4) void linear_kernel(
    const float* __restrict__ x, const float* __restrict__ w,
    const float* __restrict__ bias, float* __restrict__ y) {
  // W in A-fragment order (A = W^T tile):
  //   lds_w[((kk*8+nt)*64 + qk*16+lc)*8 + j] = bf16( W[kk*32+qk*8+j][nt*16+lc] )
  __shared__ __align__(16) unsigned short lds_w[128 * 128];

  const int t = threadIdx.x;

  // ---- stage W once per block (L2-hot column reads, conflict-free b128 writes)
  #pragma unroll
  for (int gi = 0; gi < 8; ++gi) {
    int g = t + 256 * gi;            // 16-byte group 0..2047
    int fragid = g >> 6;             // kk*8+nt
    int slot   = g & 63;             // qk*16+lc
    int kk = fragid >> 3, nt = fragid & 7;
    int qk = slot >> 4,   lc = slot & 15;
    const float* wp = w + (size_t)(kk * 32 + qk * 8) * 128 + nt * 16 + lc;
    unsigned short tmp[8];
    #pragma unroll
    for (int j = 0; j < 8; ++j) tmp[j] = f2bf(wp[(size_t)j * 128]);
    *(bf16x8*)&lds_w[(size_t)g * 8] = *(const bf16x8*)tmp;
  }

  const int lane = t & 63;
  const int wave = t >> 6;
  const int col  = lane & 15;                  // y-row within 16-row wave tile
  const int quad = lane >> 4;

  // bias fragment: lane's 4 outputs are y cols nt*16 + quad*4 .. +3
  f32x4 bfrag[8];
  #pragma unroll
  for (int nt = 0; nt < 8; ++nt)
    bfrag[nt] = *(const f32x4*)(bias + nt * 16 + quad * 4);

  __syncthreads();

  const size_t lane_off = (size_t)(wave * 16 + col) * 128 + quad * 8;

  // ---- software pipeline over 4 chunks of 64 rows ----
  int c = blockIdx.x;

  // prologue: load chunk c, convert
  f32x4 nxt[8];
  {
    const float* xp = x + (size_t)c * 64 * 128 + lane_off;
    #pragma unroll
    for (int kk = 0; kk < 4; ++kk) {
      nxt[2*kk]   = *(const f32x4*)(xp + kk * 32);
      nxt[2*kk+1] = *(const f32x4*)(xp + kk * 32 + 4);
    }
  }
  bf16x8 xf[4];
  cvt8(nxt, xf);

  while (c < NCHUNK) {
    const int cn = c + GRID;
    if (cn < NCHUNK) {                         // block-uniform branch
      const float* xq = x + (size_t)cn * 64 * 128 + lane_off;
      #pragma unroll
      for (int kk = 0; kk < 4; ++kk) {
        nxt[2*kk]   = *(const f32x4*)(xq + kk * 32);
        nxt[2*kk+1] = *(const f32x4*)(xq + kk * 32 + 4);
      }
    }

    // compute + store chunk c from bf16 regs (prefetch in flight)
    float* yp = y + (size_t)c * 64 * 128 + (size_t)(wave * 16 + col) * 128;
    #pragma unroll
    for (int nt = 0; nt < 8; ++nt) {
      f32x4 acc = bfrag[nt];
      #pragma unroll
      for (int kk = 0; kk < 4; ++kk) {
        bf16x8 wf = *(const bf16x8*)&lds_w[((kk * 8 + nt) * 64 + lane) * 8];
        acc = __builtin_amdgcn_mfma_f32_16x16x32_bf16(wf, xf[kk], acc, 0, 0, 0);
      }
      __builtin_nontemporal_store(acc, (f32x4*)(yp + nt * 16 + quad * 4));
    }

    cvt8(nxt, xf);                             // convert prefetched chunk
    c = cn;
  }
}

extern "C" void kernel_launch(void* const* d_in, const int* in_sizes, int n_in,
                              void* d_out, int out_size, void* d_ws, size_t ws_size,
                              hipStream_t stream) {
  const float* x    = (const float*)d_in[0];
  const float* w    = (const float*)d_in[1];
  const float* bias = (const float*)d_in[2];
  float* y = (float*)d_out;
  linear_kernel<<<GRID, 256, 0, stream>>>(x, w, bias, y);
}

// Round 4
// 253.855 us; speedup vs baseline: 1.2925x; 1.2925x over previous
//
#include <hip/hip_runtime.h>
#include <stdint.h>

// y[m][n] = sum_k x[m][k] * W[k][n] + b[n]
// M=262144, K=128, N=128. Floor: ~134 MB x-read + ~134 MB y-write @6.3 TB/s ~ 43 us.
// bf16 MFMA 16x16x32, swapped operands (A=W^T, B=x) -> lane's 4 C-regs are 4
// consecutive y columns -> f32x4 nontemporal stores.
// Grid = 1024 = exact residency (4 blocks/CU). Block owns 256 CONTIGUOUS rows
// (r2's locality) and walks them in 4 chunks of 64 rows with a register
// software pipeline (r3's latency hiding, minus r3's 33.5 MB stride jumps).

typedef __attribute__((ext_vector_type(8))) short bf16x8;   // 8 bf16 = 4 VGPRs
typedef __attribute__((ext_vector_type(4))) float f32x4;    // MFMA C/D

__device__ inline unsigned short f2bf(float f) {
  union { float f; uint32_t u; } v; v.f = f;
  uint32_t r = v.u + 0x7fffu + ((v.u >> 16) & 1u);
  return (unsigned short)(r >> 16);
}

__device__ inline void cvt8(const f32x4* src, bf16x8* dst) {
  #pragma unroll
  for (int kk = 0; kk < 4; ++kk) {
    bf16x8 av;
    av[0] = f2bf(src[2*kk][0]); av[1] = f2bf(src[2*kk][1]);
    av[2] = f2bf(src[2*kk][2]); av[3] = f2bf(src[2*kk][3]);
    av[4] = f2bf(src[2*kk+1][0]); av[5] = f2bf(src[2*kk+1][1]);
    av[6] = f2bf(src[2*kk+1][2]); av[7] = f2bf(src[2*kk+1][3]);
    dst[kk] = av;
  }
}

__global__ __launch_bounds__(256, 4) void linear_kernel(
    const float* __restrict__ x, const float* __restrict__ w,
    const float* __restrict__ bias, float* __restrict__ y) {
  // W in A-fragment order (A = W^T tile):
  //   lds_w[((kk*8+nt)*64 + qk*16+lc)*8 + j] = bf16( W[kk*32+qk*8+j][nt*16+lc] )
  __shared__ __align__(16) unsigned short lds_w[128 * 128];

  const int t = threadIdx.x;

  // ---- stage W once per block (L2-hot column reads, conflict-free b128 writes)
  #pragma unroll
  for (int gi = 0; gi < 8; ++gi) {
    int g = t + 256 * gi;            // 16-byte group 0..2047
    int fragid = g >> 6;             // kk*8+nt
    int slot   = g & 63;             // qk*16+lc
    int kk = fragid >> 3, nt = fragid & 7;
    int qk = slot >> 4,   lc = slot & 15;
    const float* wp = w + (size_t)(kk * 32 + qk * 8) * 128 + nt * 16 + lc;
    unsigned short tmp[8];
    #pragma unroll
    for (int j = 0; j < 8; ++j) tmp[j] = f2bf(wp[(size_t)j * 128]);
    *(bf16x8*)&lds_w[(size_t)g * 8] = *(const bf16x8*)tmp;
  }

  const int lane = t & 63;
  const int wave = t >> 6;
  const int col  = lane & 15;                  // y-row within 16-row wave tile
  const int quad = lane >> 4;

  // bias fragment: lane's 4 outputs are y cols nt*16 + quad*4 .. +3
  f32x4 bfrag[8];
  #pragma unroll
  for (int nt = 0; nt < 8; ++nt)
    bfrag[nt] = *(const f32x4*)(bias + nt * 16 + quad * 4);

  __syncthreads();

  // block owns rows [blockIdx.x*256, +256); wave's lane offset within a chunk
  const size_t lane_off = (size_t)(wave * 16 + col) * 128 + quad * 8;
  const float* xb = x + (size_t)blockIdx.x * 256 * 128;
  float*       yb = y + (size_t)blockIdx.x * 256 * 128;

  // ---- software pipeline over 4 contiguous chunks of 64 rows ----
  f32x4 nxt[8];
  {
    const float* xp = xb + lane_off;           // chunk 0
    #pragma unroll
    for (int kk = 0; kk < 4; ++kk) {
      nxt[2*kk]   = *(const f32x4*)(xp + kk * 32);
      nxt[2*kk+1] = *(const f32x4*)(xp + kk * 32 + 4);
    }
  }
  bf16x8 xf[4];
  cvt8(nxt, xf);

  #pragma unroll
  for (int c = 0; c < 4; ++c) {
    if (c < 3) {                               // prefetch next contiguous chunk
      const float* xq = xb + (size_t)(c + 1) * 64 * 128 + lane_off;
      #pragma unroll
      for (int kk = 0; kk < 4; ++kk) {
        nxt[2*kk]   = *(const f32x4*)(xq + kk * 32);
        nxt[2*kk+1] = *(const f32x4*)(xq + kk * 32 + 4);
      }
    }

    // compute + store chunk c from bf16 regs (prefetch in flight)
    float* yp = yb + (size_t)c * 64 * 128 + (size_t)(wave * 16 + col) * 128;
    #pragma unroll
    for (int nt = 0; nt < 8; ++nt) {
      f32x4 acc = bfrag[nt];
      #pragma unroll
      for (int kk = 0; kk < 4; ++kk) {
        bf16x8 wf = *(const bf16x8*)&lds_w[((kk * 8 + nt) * 64 + lane) * 8];
        acc = __builtin_amdgcn_mfma_f32_16x16x32_bf16(wf, xf[kk], acc, 0, 0, 0);
      }
      __builtin_nontemporal_store(acc, (f32x4*)(yp + nt * 16 + quad * 4));
    }

    cvt8(nxt, xf);                             // convert prefetched chunk
  }
}

extern "C" void kernel_launch(void* const* d_in, const int* in_sizes, int n_in,
                              void* d_out, int out_size, void* d_ws, size_t ws_size,
                              hipStream_t stream) {
  const float* x    = (const float*)d_in[0];
  const float* w    = (const float*)d_in[1];
  const float* bias = (const float*)d_in[2];
  float* y = (float*)d_out;
  linear_kernel<<<1024, 256, 0, stream>>>(x, w, bias, y);
}